// Round 6
// baseline (365.489 us; speedup 1.0000x reference)
//
#include <hip/hip_runtime.h>
#include <stdint.h>

// Problem constants (PureSAGEConv): N=50000, C_in=512, C_out=512, E=800000
#define CI 512
#define CO 512
#define CPAD 8   // counter padding stride (ints): 4 counters per 128B line

typedef __attribute__((ext_vector_type(4))) float f32x4;
typedef __attribute__((ext_vector_type(8))) __bf16 bf16x8;

#define AS1 __attribute__((address_space(1)))
#define AS3 __attribute__((address_space(3)))

__device__ __forceinline__ unsigned short f2bf_bits(float f) {
  union { float f; unsigned int u; } v; v.f = f;
  unsigned int u = v.u;
  unsigned int lsb = (u >> 16) & 1u;
  u += 0x7fffu + lsb;                 // round-to-nearest-even
  return (unsigned short)(u >> 16);
}

// ---- merged: convert x, convert W, degree histogram (block-range split) ----
__global__ void k_prep(const float* __restrict__ x, unsigned short* __restrict__ xb, int nx4,
                       const float* __restrict__ W, unsigned short* __restrict__ Wb, int nw4,
                       const int* __restrict__ dst, int* __restrict__ cnt, int E,
                       int bx, int bw) {
  const int b = blockIdx.x;
  if (b < bx) {
    int i = b * 256 + threadIdx.x;
    if (i < nx4) {
      float4 v = reinterpret_cast<const float4*>(x)[i];
      ushort4 o;
      o.x = f2bf_bits(v.x); o.y = f2bf_bits(v.y);
      o.z = f2bf_bits(v.z); o.w = f2bf_bits(v.w);
      reinterpret_cast<ushort4*>(xb)[i] = o;
    }
  } else if (b < bx + bw) {
    int i = (b - bx) * 256 + threadIdx.x;
    if (i < nw4) {
      float4 v = reinterpret_cast<const float4*>(W)[i];
      ushort4 o;
      o.x = f2bf_bits(v.x); o.y = f2bf_bits(v.y);
      o.z = f2bf_bits(v.z); o.w = f2bf_bits(v.w);
      reinterpret_cast<ushort4*>(Wb)[i] = o;
    }
  } else {
    int e = (b - bx - bw) * 256 + threadIdx.x;
    if (e < E) atomicAdd(&cnt[dst[e] * CPAD], 1);
  }
}

// ---- per-256-node block sums of (padded) degree counters ----
__global__ void k_bsum(const int* __restrict__ cnt, int* __restrict__ bsum, int n) {
  int t = threadIdx.x;
  int i = blockIdx.x * 256 + t;
  int v = (i < n) ? cnt[(size_t)i * CPAD] : 0;
  #pragma unroll
  for (int off = 32; off; off >>= 1) v += __shfl_down(v, off, 64);
  __shared__ int ws[4];
  if ((t & 63) == 0) ws[t >> 6] = v;
  __syncthreads();
  if (t == 0) bsum[blockIdx.x] = ws[0] + ws[1] + ws[2] + ws[3];
}

// ---- merged scan: each block redundantly scans bsum (nb<=256), then
//      block-local scan of padded cnt -> rowptr (exclusive, rowptr[0]=0) ----
__global__ void k_scanf(const int* __restrict__ cnt, const int* __restrict__ bsum,
                        int* __restrict__ rowptr, int n, int nb) {
  int t = threadIdx.x, lane = t & 63, w = t >> 6;
  __shared__ int ws1[4], ws2[4], sboff;

  int v0 = (t < nb) ? bsum[t] : 0;
  int s0 = v0;
  #pragma unroll
  for (int off = 1; off < 64; off <<= 1) {
    int u = __shfl_up(s0, off, 64);
    if (lane >= off) s0 += u;
  }
  if (lane == 63) ws1[w] = s0;
  __syncthreads();
  if (t == blockIdx.x) {
    int add0 = 0;
    for (int j = 0; j < w; ++j) add0 += ws1[j];
    sboff = s0 + add0 - v0;            // exclusive offset for this block
  }
  __syncthreads();

  int i = blockIdx.x * 256 + t;
  int v = (i < n) ? cnt[(size_t)i * CPAD] : 0;
  int s = v;
  #pragma unroll
  for (int off = 1; off < 64; off <<= 1) {
    int u = __shfl_up(s, off, 64);
    if (lane >= off) s += u;
  }
  if (lane == 63) ws2[w] = s;
  __syncthreads();
  int add = sboff;
  for (int j = 0; j < w; ++j) add += ws2[j];
  if (i < n) rowptr[i + 1] = s + add;
  if (i == 0) rowptr[0] = 0;
}

// ---- counting-sort fill of CSR neighbor lists (padded cursors) ----
__global__ void k_fill(const int* __restrict__ src, const int* __restrict__ dst,
                       const int* __restrict__ rowptr, int* __restrict__ cursor,
                       int* __restrict__ csr, int E) {
  int e = blockIdx.x * 256 + threadIdx.x;
  if (e < E) {
    int d = dst[e];
    int pos = atomicAdd(&cursor[(size_t)d * CPAD], 1);
    csr[rowptr[d] + pos] = src[e];
  }
}

// ---- bf16 accumulate helper ----
__device__ __forceinline__ void acc8(float* s, uint4 r) {
  const unsigned int u[4] = {r.x, r.y, r.z, r.w};
  #pragma unroll
  for (int k = 0; k < 4; ++k) {
    union { unsigned int u; float f; } lo, hi;
    lo.u = u[k] << 16;
    hi.u = u[k] & 0xffff0000u;
    s[2 * k]     += lo.f;
    s[2 * k + 1] += hi.f;
  }
}

// =====================================================================
// FUSED aggregate + GEMM. Block owns BM=64 output rows:
//   phase A: neighbor-mean of its 64 nodes -> LDS (bf16, chunk-XOR swz)
//   phase B: out[rows][512] = [xb rows | mean] . Wb^T + bias  (K=1024)
// Even blocks run the x-half K-loop (kt 0-7, no mean dep) BEFORE phase A
// to force chip-wide phase desync (half the CUs gather, half compute).
// Eliminates meanb global round-trip (102 MB) and one kernel launch.
// =====================================================================
#define BM 64

__global__ __launch_bounds__(512) void k_fused(
    const unsigned short* __restrict__ xb,
    const int* __restrict__ rowptr,
    const int* __restrict__ csr,
    const unsigned short* __restrict__ Wb,
    const float* __restrict__ bias,
    float* __restrict__ out, int Nn) {
  __shared__ unsigned short sh_mean[BM * 512];   // 64 KB
  __shared__ unsigned short sh_w[512 * 64];      // 64 KB (one BK=64 W tile)
  __shared__ unsigned short sh_ax[BM * 64];      // 8 KB  (one BK=64 A-x tile)

  const int tid = threadIdx.x;
  const int lane = tid & 63, wv = tid >> 6;      // 8 waves
  const int m0 = blockIdx.x * BM;
  const int wm = wv >> 2, wn = wv & 3;           // 2M x 4N wave grid
  const int lrow = lane & 15, lj = lane >> 4;

  f32x4 acc[2][8] = {};

  // ---- phase A: aggregate 8 nodes per wave into sh_mean (swizzled) ----
  auto phaseA = [&]() {
    const size_t laneoff = (size_t)lane * 8;
    for (int i = 0; i < 8; ++i) {
      const int r = wv * 8 + i;                  // local row; r&7 == i
      const int node = m0 + r;
      uint4 wvv = {0u, 0u, 0u, 0u};
      if (node < Nn) {
        const int beg = rowptr[node];
        const int deg = rowptr[node + 1] - beg;
        float s[8] = {};
        for (int base = 0; base < deg; base += 64) {
          const int rem = deg - base;
          const int cnt = rem < 64 ? rem : 64;
          int nidx = 0;
          if (lane < cnt) nidx = csr[beg + base + lane];
          int j = 0;
          for (; j + 4 <= cnt; j += 4) {
            int u0 = __shfl(nidx, j, 64);
            int u1 = __shfl(nidx, j + 1, 64);
            int u2 = __shfl(nidx, j + 2, 64);
            int u3 = __shfl(nidx, j + 3, 64);
            uint4 r0 = *reinterpret_cast<const uint4*>(xb + (size_t)u0 * CI + laneoff);
            uint4 r1 = *reinterpret_cast<const uint4*>(xb + (size_t)u1 * CI + laneoff);
            uint4 r2 = *reinterpret_cast<const uint4*>(xb + (size_t)u2 * CI + laneoff);
            uint4 r3 = *reinterpret_cast<const uint4*>(xb + (size_t)u3 * CI + laneoff);
            acc8(s, r0); acc8(s, r1); acc8(s, r2); acc8(s, r3);
          }
          for (; j < cnt; ++j) {
            int u = __shfl(nidx, j, 64);
            uint4 rr = *reinterpret_cast<const uint4*>(xb + (size_t)u * CI + laneoff);
            acc8(s, rr);
          }
        }
        const float inv = 1.f / fmaxf((float)deg, 1.f);
        unsigned short ob[8];
        #pragma unroll
        for (int k = 0; k < 8; ++k) ob[k] = f2bf_bits(s[k] * inv);
        wvv.x = (unsigned int)ob[0] | ((unsigned int)ob[1] << 16);
        wvv.y = (unsigned int)ob[2] | ((unsigned int)ob[3] << 16);
        wvv.z = (unsigned int)ob[4] | ((unsigned int)ob[5] << 16);
        wvv.w = (unsigned int)ob[6] | ((unsigned int)ob[7] << 16);
      }
      // lane holds logical chunk `lane`; store at chunk lane ^ (r&7)
      *reinterpret_cast<uint4*>(&sh_mean[r * 512 + ((lane ^ i) * 8)]) = wvv;
    }
    __syncthreads();   // mean complete before any K>=512 fragment read
  };

  // ---- phase B K-loop over BK=64 tiles; kt<8 -> A from xb, else sh_mean ----
  int ar = tid >> 3;                   // staging: A row 0..63
  int ga = m0 + ar; if (ga >= Nn) ga = Nn - 1;
  const int acol = ((tid & 7) ^ (ar & 7)) * 8;

  auto doK = [&](int kt0, int kt1) {
    for (int kt = kt0; kt < kt1; ++kt) {
      __syncthreads();                 // previous W/A tile fully consumed
      #pragma unroll
      for (int i = 0; i < 8; ++i) {    // stage W tile: 512 rows x 64 k
        int idx = i * 512 + tid;
        int nr = idx >> 3, sc = idx & 7;
        __builtin_amdgcn_global_load_lds(
          (const AS1 unsigned int*)(uintptr_t)(Wb + (size_t)nr * (2 * CI) + kt * 64 + ((sc ^ (nr & 7)) * 8)),
          (AS3 unsigned int*)(uintptr_t)(&sh_w[(size_t)idx * 8]), 16, 0, 0);
      }
      if (kt < 8)                      // stage A-x tile: 64 rows x 64 k
        __builtin_amdgcn_global_load_lds(
          (const AS1 unsigned int*)(uintptr_t)(xb + (size_t)ga * CI + kt * 64 + acol),
          (AS3 unsigned int*)(uintptr_t)(&sh_ax[(size_t)tid * 8]), 16, 0, 0);
      __syncthreads();                 // drains vmcnt -> tiles ready
      #pragma unroll
      for (int kk = 0; kk < 2; ++kk) {
        const int cc = kk * 4 + lj;    // chunk 0..7 within BK=64 row
        bf16x8 af[2], bf[8];
        #pragma unroll
        for (int mi = 0; mi < 2; ++mi) {
          const int rr = wm * 32 + mi * 16 + lrow;
          if (kt < 8) {
            af[mi] = *reinterpret_cast<const bf16x8*>(&sh_ax[rr * 64 + ((cc ^ (rr & 7)) * 8)]);
          } else {
            const int ccm = (kt - 8) * 8 + cc;           // 0..63
            af[mi] = *reinterpret_cast<const bf16x8*>(&sh_mean[rr * 512 + ((ccm ^ (rr & 7)) * 8)]);
          }
        }
        #pragma unroll
        for (int ni = 0; ni < 8; ++ni) {
          const int nr = wn * 128 + ni * 16 + lrow;
          bf[ni] = *reinterpret_cast<const bf16x8*>(&sh_w[nr * 64 + ((cc ^ (nr & 7)) * 8)]);
        }
        __builtin_amdgcn_s_setprio(1);
        #pragma unroll
        for (int mi = 0; mi < 2; ++mi)
          #pragma unroll
          for (int ni = 0; ni < 8; ++ni)
            acc[mi][ni] = __builtin_amdgcn_mfma_f32_16x16x32_bf16(af[mi], bf[ni], acc[mi][ni], 0, 0, 0);
        __builtin_amdgcn_s_setprio(0);
      }
    }
  };

  if (blockIdx.x & 1) {
    phaseA();
    doK(0, 16);
  } else {
    doK(0, 8);        // x-half first: no mean dependency -> phase desync
    phaseA();
    doK(8, 16);
  }

  // ---- epilogue: LDS-staged (overlay sh_w), linear float4 stores ----
  __syncthreads();
  float* ldc = reinterpret_cast<float*>(sh_w);   // 16 rows x 516 pitch = 33 KB
  float bv[8];
  #pragma unroll
  for (int ni = 0; ni < 8; ++ni) bv[ni] = bias[wn * 128 + ni * 16 + lrow];

  #pragma unroll
  for (int c = 0; c < 4; ++c) {        // 16-row chunks
    if (wm == (c >> 1)) {
      const int mi = c & 1;
      #pragma unroll
      for (int ni = 0; ni < 8; ++ni)
        #pragma unroll
        for (int j = 0; j < 4; ++j)
          ldc[(lj * 4 + j) * 516 + wn * 128 + ni * 16 + lrow] = acc[mi][ni][j] + bv[ni];
    }
    __syncthreads();
    #pragma unroll
    for (int p = 0; p < 4; ++p) {
      int idx = p * 512 + tid;         // 0..2047
      int rl = idx >> 7;               // 0..15
      int c4 = (idx & 127) << 2;       // 0..508
      int row = m0 + c * 16 + rl;
      if (row < Nn) {
        float4 v = *reinterpret_cast<const float4*>(&ldc[rl * 516 + c4]);
        *reinterpret_cast<float4*>(&out[(size_t)row * CO + c4]) = v;
      }
    }
    __syncthreads();
  }
}

extern "C" void kernel_launch(void* const* d_in, const int* in_sizes, int n_in,
                              void* d_out, int out_size, void* d_ws, size_t ws_size,
                              hipStream_t stream) {
  (void)n_in; (void)out_size; (void)ws_size;
  const float* x    = (const float*)d_in[0];
  const int*   ei   = (const int*)d_in[1];
  const float* W    = (const float*)d_in[2];
  const float* bias = (const float*)d_in[3];
  float* out = (float*)d_out;

  const int Nn = in_sizes[0] / CI;     // 50000
  const int E  = in_sizes[1] / 2;      // 800000
  const int* src = ei;
  const int* dst = ei + E;

  const int nblk = (Nn + 255) / 256;   // 196 scan blocks

  // workspace layout (~62 MB):
  int* cnt    = (int*)d_ws;                      // [Nn*CPAD]
  int* cursor = cnt + (size_t)Nn * CPAD;         // [Nn*CPAD]
  int* rowptr = cursor + (size_t)Nn * CPAD;      // [Nn+1]
  int* bsum   = rowptr + (Nn + 1);               // [nblk]
  int* csr    = bsum + nblk;                     // [E]
  uintptr_t p = (uintptr_t)(csr + E);
  p = (p + 255) & ~(uintptr_t)255;
  unsigned short* xb = (unsigned short*)p;              // [Nn*CI] bf16
  unsigned short* Wb = xb + (size_t)Nn * CI;            // [CO*2CI] bf16

  hipMemsetAsync(cnt, 0, (size_t)2 * Nn * CPAD * sizeof(int), stream);  // cnt + cursor

  const int nx4 = (Nn * CI) / 4;          // 6,400,000
  const int nw4 = (CO * 2 * CI) / 4;      // 131,072
  const int bx = (nx4 + 255) / 256;       // 25000
  const int bw = (nw4 + 255) / 256;       // 512
  const int be = (E + 255) / 256;         // 3125
  k_prep<<<bx + bw + be, 256, 0, stream>>>(x, xb, nx4, W, Wb, nw4, dst, cnt, E, bx, bw);
  k_bsum<<<nblk, 256, 0, stream>>>(cnt, bsum, Nn);
  k_scanf<<<nblk, 256, 0, stream>>>(cnt, bsum, rowptr, Nn, nblk);
  k_fill<<<(E + 255) / 256, 256, 0, stream>>>(src, dst, rowptr, cursor, csr, E);

  const int nfb = (Nn + BM - 1) / BM;     // 782 fused blocks
  k_fused<<<nfb, 512, 0, stream>>>(xb, rowptr, csr, Wb, bias, out, Nn);
}

// Round 7
// 353.254 us; speedup vs baseline: 1.0346x; 1.0346x over previous
//
#include <hip/hip_runtime.h>
#include <stdint.h>

// Problem constants (PureSAGEConv): N=50000, C_in=512, C_out=512, E=800000
#define CI 512
#define CO 512
#define CPAD 8   // counter padding stride (ints): 4 counters per 128B line

typedef __attribute__((ext_vector_type(4))) float f32x4;
typedef __attribute__((ext_vector_type(8))) __bf16 bf16x8;

#define AS1 __attribute__((address_space(1)))
#define AS3 __attribute__((address_space(3)))

__device__ __forceinline__ unsigned short f2bf_bits(float f) {
  union { float f; unsigned int u; } v; v.f = f;
  unsigned int u = v.u;
  unsigned int lsb = (u >> 16) & 1u;
  u += 0x7fffu + lsb;                 // round-to-nearest-even
  return (unsigned short)(u >> 16);
}

// ---- merged: convert x, convert W, degree histogram (block-range split) ----
__global__ void k_prep(const float* __restrict__ x, unsigned short* __restrict__ xb, int nx4,
                       const float* __restrict__ W, unsigned short* __restrict__ Wb, int nw4,
                       const int* __restrict__ dst, int* __restrict__ cnt, int E,
                       int bx, int bw) {
  const int b = blockIdx.x;
  if (b < bx) {
    int i = b * 256 + threadIdx.x;
    if (i < nx4) {
      float4 v = reinterpret_cast<const float4*>(x)[i];
      ushort4 o;
      o.x = f2bf_bits(v.x); o.y = f2bf_bits(v.y);
      o.z = f2bf_bits(v.z); o.w = f2bf_bits(v.w);
      reinterpret_cast<ushort4*>(xb)[i] = o;
    }
  } else if (b < bx + bw) {
    int i = (b - bx) * 256 + threadIdx.x;
    if (i < nw4) {
      float4 v = reinterpret_cast<const float4*>(W)[i];
      ushort4 o;
      o.x = f2bf_bits(v.x); o.y = f2bf_bits(v.y);
      o.z = f2bf_bits(v.z); o.w = f2bf_bits(v.w);
      reinterpret_cast<ushort4*>(Wb)[i] = o;
    }
  } else {
    int e = (b - bx - bw) * 256 + threadIdx.x;
    if (e < E) atomicAdd(&cnt[dst[e] * CPAD], 1);
  }
}

// ---- per-256-node block sums of (padded) degree counters ----
__global__ void k_bsum(const int* __restrict__ cnt, int* __restrict__ bsum, int n) {
  int t = threadIdx.x;
  int i = blockIdx.x * 256 + t;
  int v = (i < n) ? cnt[(size_t)i * CPAD] : 0;
  #pragma unroll
  for (int off = 32; off; off >>= 1) v += __shfl_down(v, off, 64);
  __shared__ int ws[4];
  if ((t & 63) == 0) ws[t >> 6] = v;
  __syncthreads();
  if (t == 0) bsum[blockIdx.x] = ws[0] + ws[1] + ws[2] + ws[3];
}

// ---- merged scan: each block redundantly scans bsum (nb<=256), then
//      block-local scan of padded cnt -> rowptr (exclusive, rowptr[0]=0) ----
__global__ void k_scanf(const int* __restrict__ cnt, const int* __restrict__ bsum,
                        int* __restrict__ rowptr, int n, int nb) {
  int t = threadIdx.x, lane = t & 63, w = t >> 6;
  __shared__ int ws1[4], ws2[4], sboff;

  int v0 = (t < nb) ? bsum[t] : 0;
  int s0 = v0;
  #pragma unroll
  for (int off = 1; off < 64; off <<= 1) {
    int u = __shfl_up(s0, off, 64);
    if (lane >= off) s0 += u;
  }
  if (lane == 63) ws1[w] = s0;
  __syncthreads();
  if (t == blockIdx.x) {
    int add0 = 0;
    for (int j = 0; j < w; ++j) add0 += ws1[j];
    sboff = s0 + add0 - v0;            // exclusive offset for this block
  }
  __syncthreads();

  int i = blockIdx.x * 256 + t;
  int v = (i < n) ? cnt[(size_t)i * CPAD] : 0;
  int s = v;
  #pragma unroll
  for (int off = 1; off < 64; off <<= 1) {
    int u = __shfl_up(s, off, 64);
    if (lane >= off) s += u;
  }
  if (lane == 63) ws2[w] = s;
  __syncthreads();
  int add = sboff;
  for (int j = 0; j < w; ++j) add += ws2[j];
  if (i < n) rowptr[i + 1] = s + add;
  if (i == 0) rowptr[0] = 0;
}

// ---- counting-sort fill of CSR neighbor lists (padded cursors, u16 src) ----
__global__ void k_fill(const int* __restrict__ src, const int* __restrict__ dst,
                       const int* __restrict__ rowptr, int* __restrict__ cursor,
                       unsigned short* __restrict__ csr, int E) {
  int e = blockIdx.x * 256 + threadIdx.x;
  if (e < E) {
    int d = dst[e];
    int pos = atomicAdd(&cursor[(size_t)d * CPAD], 1);
    csr[rowptr[d] + pos] = (unsigned short)src[e];   // src < 50000 < 65536
  }
}

// ---- bf16 accumulate helper ----
__device__ __forceinline__ void acc8(float* s, uint4 r) {
  const unsigned int u[4] = {r.x, r.y, r.z, r.w};
  #pragma unroll
  for (int k = 0; k < 4; ++k) {
    union { unsigned int u; float f; } lo, hi;
    lo.u = u[k] << 16;
    hi.u = u[k] & 0xffff0000u;
    s[2 * k]     += lo.f;
    s[2 * k + 1] += hi.f;
  }
}

// =====================================================================
// XCD channel-sliced aggregate. Slice s = channels [s*64,(s+1)*64) is
// processed ONLY by blocks with bid%8==s -> lands on XCD s (dispatcher
// round-robin). Per-XCD gather footprint drops 51MB -> 6.4MB (mostly
// L2-resident). Wave = 8 groups x 8 lanes; group g gathers neighbor
// j+g's 128B slice (16B/lane); 3-level shfl_xor group reduce.
// Mean stored SLICED: meanS[s][node][64ch].
// =====================================================================
__global__ __launch_bounds__(512) void k_aggregate(
    const unsigned short* __restrict__ xb,
    const int* __restrict__ rowptr,
    const unsigned short* __restrict__ csr,
    unsigned short* __restrict__ meanS, int Nn) {
  const int s  = blockIdx.x & 7;                 // slice == XCD (bid%8)
  const int ng = blockIdx.x >> 3;
  const int wv = threadIdx.x >> 6;               // 8 waves/block
  const int lane = threadIdx.x & 63;
  const int g = lane >> 3, li = lane & 7;
  const int node = ng * 8 + wv;
  if (node >= Nn) return;

  const int beg = rowptr[node];
  const int deg = rowptr[node + 1] - beg;
  float acc[8] = {};
  const unsigned short* __restrict__ xs = xb + s * 64 + li * 8;

  for (int j = 0; j < deg; j += 16) {
    int nidx = 0;
    if (lane < 16 && j + lane < deg) nidx = (int)csr[beg + j + lane];
    int u0 = __shfl(nidx, g, 64);
    int u1 = __shfl(nidx, g + 8, 64);
    if (j + g < deg) {
      uint4 r = *reinterpret_cast<const uint4*>(xs + (size_t)u0 * CI);
      acc8(acc, r);
    }
    if (j + 8 + g < deg) {
      uint4 r = *reinterpret_cast<const uint4*>(xs + (size_t)u1 * CI);
      acc8(acc, r);
    }
  }

  // reduce across the 8 groups
  #pragma unroll
  for (int off = 8; off < 64; off <<= 1)
    #pragma unroll
    for (int k = 0; k < 8; ++k)
      acc[k] += __shfl_xor(acc[k], off, 64);

  if (g == 0) {
    const float inv = 1.f / fmaxf((float)deg, 1.f);
    unsigned short ob[8];
    #pragma unroll
    for (int k = 0; k < 8; ++k) ob[k] = f2bf_bits(acc[k] * inv);
    uint4 w;
    w.x = (unsigned int)ob[0] | ((unsigned int)ob[1] << 16);
    w.y = (unsigned int)ob[2] | ((unsigned int)ob[3] << 16);
    w.z = (unsigned int)ob[4] | ((unsigned int)ob[5] << 16);
    w.w = (unsigned int)ob[6] | ((unsigned int)ob[7] << 16);
    *reinterpret_cast<uint4*>(meanS + ((size_t)s * Nn + node) * 64 + li * 8) = w;
  }
}

// ---- bf16 MFMA GEMM, pipelined: out[M][512] = [xb|mean][M][1024].Wb^T + b ----
// BM=256 BN=128 BK=64, 8 waves (512 thr), 3-slot LDS ring (144 KB),
// counted vmcnt(12). Mean half read from SLICED layout meanS[8][Nn][64].
#define BM 256
#define BN 128
#define BK 64
#define SLOT_SH 24576     // shorts per slot: A 16384 (32KB) + B 8192 (16KB)
#define BOFF 16384        // B base within slot (shorts)
#define EPAD 132          // f32 row pitch for epilogue LDS tile

#define WAITV(N) asm volatile("s_waitcnt vmcnt(" #N ")" ::: "memory")

__global__ __launch_bounds__(512) void k_gemm(
    const unsigned short* __restrict__ xb,
    const unsigned short* __restrict__ meanS,
    const unsigned short* __restrict__ Wb,
    const float* __restrict__ bias,
    float* __restrict__ out, int M) {
  __shared__ unsigned short lds[3 * SLOT_SH];   // 144 KB
  const int tid = threadIdx.x;

  // grid = 196 m-tiles x 4 n-tiles = 784 = 8*98: chunked XCD swizzle
  const int wg = (blockIdx.x & 7) * 98 + (blockIdx.x >> 3);
  const int tm = wg >> 2, tn = wg & 3;
  const int m0 = tm * BM, n0 = tn * BN;
  const int lane = tid & 63, wvid = tid >> 6;
  const int wm = wvid >> 2, wn = wvid & 3;      // 2M x 4N waves
  const int lrow = lane & 15;

  // staging geometry (T2 chunk swizzle: src chunk = stored-chunk ^ (row&7))
  int gra[4], asrc8[4];
  #pragma unroll
  for (int i = 0; i < 4; ++i) {
    int idx = i * 512 + tid;
    int r = idx >> 3;
    asrc8[i] = ((idx & 7) ^ (r & 7)) * 8;
    int g = m0 + r;
    gra[i] = g < M ? g : M - 1;
  }
  int brow[2], bsrc8[2];
  #pragma unroll
  for (int i = 0; i < 2; ++i) {
    int idx = i * 512 + tid;
    int r = idx >> 3;
    brow[i] = r;
    bsrc8[i] = ((idx & 7) ^ (r & 7)) * 8;
  }

  const size_t Nn64 = (size_t)M * 64;

  f32x4 acc[8][2] = {};

  // stage K-tile kt into slot sl
  auto stage = [&](int kt, int sl) {
    unsigned short* sa = &lds[sl * SLOT_SH];
    unsigned short* sb = sa + BOFF;
    if (kt < 8) {
      const int ka = kt * 64;
      #pragma unroll
      for (int i = 0; i < 4; ++i)
        __builtin_amdgcn_global_load_lds(
          (const AS1 unsigned int*)(uintptr_t)(xb + (size_t)gra[i] * CI + ka + asrc8[i]),
          (AS3 unsigned int*)(uintptr_t)(&sa[(size_t)(i * 512 + tid) * 8]), 16, 0, 0);
    } else {
      const unsigned short* __restrict__ A = meanS + (size_t)(kt - 8) * Nn64;
      #pragma unroll
      for (int i = 0; i < 4; ++i)
        __builtin_amdgcn_global_load_lds(
          (const AS1 unsigned int*)(uintptr_t)(A + (size_t)gra[i] * 64 + asrc8[i]),
          (AS3 unsigned int*)(uintptr_t)(&sa[(size_t)(i * 512 + tid) * 8]), 16, 0, 0);
    }
    const int kw = kt * 64;
    #pragma unroll
    for (int i = 0; i < 2; ++i)
      __builtin_amdgcn_global_load_lds(
        (const AS1 unsigned int*)(uintptr_t)(Wb + (size_t)(n0 + brow[i]) * (2 * CI) + kw + bsrc8[i]),
        (AS3 unsigned int*)(uintptr_t)(&sb[(size_t)(i * 512 + tid) * 8]), 16, 0, 0);
  };

  auto compute = [&](int sl) {
    const unsigned short* __restrict__ La = &lds[sl * SLOT_SH];
    const unsigned short* __restrict__ Lb = La + BOFF;
    #pragma unroll
    for (int kk = 0; kk < 2; ++kk) {
      const int crd = kk * 4 + (lane >> 4);
      bf16x8 af[8], bf[2];
      #pragma unroll
      for (int mi = 0; mi < 8; ++mi) {
        const int rr = wm * 128 + mi * 16 + lrow;
        af[mi] = *reinterpret_cast<const bf16x8*>(&La[rr * BK + ((crd ^ (rr & 7)) * 8)]);
      }
      #pragma unroll
      for (int ni = 0; ni < 2; ++ni) {
        const int rb = wn * 32 + ni * 16 + lrow;
        bf[ni] = *reinterpret_cast<const bf16x8*>(&Lb[rb * BK + ((crd ^ (rb & 7)) * 8)]);
      }
      __builtin_amdgcn_s_setprio(1);
      #pragma unroll
      for (int mi = 0; mi < 8; ++mi)
        #pragma unroll
        for (int ni = 0; ni < 2; ++ni)
          acc[mi][ni] = __builtin_amdgcn_mfma_f32_16x16x32_bf16(af[mi], bf[ni], acc[mi][ni], 0, 0, 0);
      __builtin_amdgcn_s_setprio(0);
    }
  };

  // prologue: 2 tiles in flight
  stage(0, 0);
  stage(1, 1);

  #pragma unroll
  for (int t = 0; t < 16; ++t) {
    if (t < 14) {
      stage(t + 2, (t + 2) % 3);
      WAITV(12);                    // 12 loads (2 tiles) stay in flight
    } else if (t == 14) {
      WAITV(6);
    } else {
      WAITV(0);
    }
    __builtin_amdgcn_s_barrier();
    __builtin_amdgcn_sched_barrier(0);
    compute(t % 3);
    __builtin_amdgcn_sched_barrier(0);
    __builtin_amdgcn_s_barrier();
  }

  // ---- LDS-staged epilogue: 8 chunks of 32 rows x 128 cols ----
  __syncthreads();
  float* ldsf = reinterpret_cast<float*>(&lds[0]);   // 32*EPAD*4 = 16.9 KB
  const int lj = lane >> 4;
  float bv[2];
  #pragma unroll
  for (int ni = 0; ni < 2; ++ni) bv[ni] = bias[n0 + wn * 32 + ni * 16 + lrow];

  #pragma unroll
  for (int c = 0; c < 8; ++c) {
    if (wm == (c >> 2)) {
      #pragma unroll
      for (int mi2 = 0; mi2 < 2; ++mi2) {
        const int mi = (c & 3) * 2 + mi2;
        #pragma unroll
        for (int ni = 0; ni < 2; ++ni)
          #pragma unroll
          for (int j = 0; j < 4; ++j)
            ldsf[(mi2 * 16 + lj * 4 + j) * EPAD + wn * 32 + ni * 16 + lrow] = acc[mi][ni][j] + bv[ni];
      }
    }
    __syncthreads();
    #pragma unroll
    for (int p = 0; p < 2; ++p) {
      int linear = p * 512 + tid;           // 0..1023
      int rl = linear >> 5;                 // 0..31
      int c4 = (linear & 31) << 2;          // 0..124
      int row = m0 + c * 32 + rl;
      if (row < M) {
        float4 v = *reinterpret_cast<const float4*>(&ldsf[rl * EPAD + c4]);
        *reinterpret_cast<float4*>(&out[(size_t)row * CO + n0 + c4]) = v;
      }
    }
    __syncthreads();
  }
}

extern "C" void kernel_launch(void* const* d_in, const int* in_sizes, int n_in,
                              void* d_out, int out_size, void* d_ws, size_t ws_size,
                              hipStream_t stream) {
  (void)n_in; (void)out_size; (void)ws_size;
  const float* x    = (const float*)d_in[0];
  const int*   ei   = (const int*)d_in[1];
  const float* W    = (const float*)d_in[2];
  const float* bias = (const float*)d_in[3];
  float* out = (float*)d_out;

  const int Nn = in_sizes[0] / CI;     // 50000
  const int E  = in_sizes[1] / 2;      // 800000
  const int* src = ei;
  const int* dst = ei + E;

  const int nblk = (Nn + 255) / 256;   // 196 scan blocks

  // workspace layout (~110 MB):
  int* cnt    = (int*)d_ws;                      // [Nn*CPAD]
  int* cursor = cnt + (size_t)Nn * CPAD;         // [Nn*CPAD]
  int* rowptr = cursor + (size_t)Nn * CPAD;      // [Nn+1]
  int* bsum   = rowptr + (Nn + 1);               // [nblk]
  uintptr_t p = (uintptr_t)(bsum + nblk);
  p = (p + 255) & ~(uintptr_t)255;
  unsigned short* csr = (unsigned short*)p;             // [E] u16 src ids
  p = (uintptr_t)(csr + E);
  p = (p + 255) & ~(uintptr_t)255;
  unsigned short* xb    = (unsigned short*)p;           // [Nn*CI] bf16
  unsigned short* meanS = xb + (size_t)Nn * CI;         // [8*Nn*64] bf16 sliced
  unsigned short* Wb    = meanS + (size_t)Nn * CI;      // [CO*2CI] bf16

  hipMemsetAsync(cnt, 0, (size_t)2 * Nn * CPAD * sizeof(int), stream);  // cnt + cursor

  const int nx4 = (Nn * CI) / 4;          // 6,400,000
  const int nw4 = (CO * 2 * CI) / 4;      // 131,072
  const int bx = (nx4 + 255) / 256;       // 25000
  const int bw = (nw4 + 255) / 256;       // 512
  const int be = (E + 255) / 256;         // 3125
  k_prep<<<bx + bw + be, 256, 0, stream>>>(x, xb, nx4, W, Wb, nw4, dst, cnt, E, bx, bw);
  k_bsum<<<nblk, 256, 0, stream>>>(cnt, bsum, Nn);
  k_scanf<<<nblk, 256, 0, stream>>>(cnt, bsum, rowptr, Nn, nblk);
  k_fill<<<(E + 255) / 256, 256, 0, stream>>>(src, dst, rowptr, cursor, csr, E);

  const int nab = ((Nn + 7) / 8) * 8;     // 6250 node-groups x 8 slices
  k_aggregate<<<nab, 512, 0, stream>>>(xb, rowptr, csr, meanS, Nn);

  const int mtiles = (Nn + BM - 1) / BM;  // 196
  k_gemm<<<mtiles * (CO / BN), 512, 0, stream>>>(xb, meanS, Wb, bias, out, Nn);
}

// Round 8
// 275.589 us; speedup vs baseline: 1.3262x; 1.2818x over previous
//
#include <hip/hip_runtime.h>
#include <stdint.h>

// Problem constants (PureSAGEConv): N=50000, C_in=512, C_out=512, E=800000
#define CI 512
#define CO 512
#define CPAD 8   // counter padding stride (ints): 4 counters per 128B line

typedef __attribute__((ext_vector_type(4))) float f32x4;
typedef __attribute__((ext_vector_type(8))) __bf16 bf16x8;

#define AS1 __attribute__((address_space(1)))
#define AS3 __attribute__((address_space(3)))

__device__ __forceinline__ unsigned short f2bf_bits(float f) {
  union { float f; unsigned int u; } v; v.f = f;
  unsigned int u = v.u;
  unsigned int lsb = (u >> 16) & 1u;
  u += 0x7fffu + lsb;                 // round-to-nearest-even
  return (unsigned short)(u >> 16);
}

// ---- merged: convert x, convert W, degree histogram (block-range split) ----
__global__ void k_prep(const float* __restrict__ x, unsigned short* __restrict__ xb, int nx4,
                       const float* __restrict__ W, unsigned short* __restrict__ Wb, int nw4,
                       const int* __restrict__ dst, int* __restrict__ cnt, int E,
                       int bx, int bw) {
  const int b = blockIdx.x;
  if (b < bx) {
    int i = b * 256 + threadIdx.x;
    if (i < nx4) {
      float4 v = reinterpret_cast<const float4*>(x)[i];
      ushort4 o;
      o.x = f2bf_bits(v.x); o.y = f2bf_bits(v.y);
      o.z = f2bf_bits(v.z); o.w = f2bf_bits(v.w);
      reinterpret_cast<ushort4*>(xb)[i] = o;
    }
  } else if (b < bx + bw) {
    int i = (b - bx) * 256 + threadIdx.x;
    if (i < nw4) {
      float4 v = reinterpret_cast<const float4*>(W)[i];
      ushort4 o;
      o.x = f2bf_bits(v.x); o.y = f2bf_bits(v.y);
      o.z = f2bf_bits(v.z); o.w = f2bf_bits(v.w);
      reinterpret_cast<ushort4*>(Wb)[i] = o;
    }
  } else {
    int e = (b - bx - bw) * 256 + threadIdx.x;
    if (e < E) atomicAdd(&cnt[dst[e] * CPAD], 1);
  }
}

// ---- per-256-node block sums of (padded) degree counters ----
__global__ void k_bsum(const int* __restrict__ cnt, int* __restrict__ bsum, int n) {
  int t = threadIdx.x;
  int i = blockIdx.x * 256 + t;
  int v = (i < n) ? cnt[(size_t)i * CPAD] : 0;
  #pragma unroll
  for (int off = 32; off; off >>= 1) v += __shfl_down(v, off, 64);
  __shared__ int ws[4];
  if ((t & 63) == 0) ws[t >> 6] = v;
  __syncthreads();
  if (t == 0) bsum[blockIdx.x] = ws[0] + ws[1] + ws[2] + ws[3];
}

// ---- merged scan: each block redundantly scans bsum (nb<=256), then
//      block-local scan of padded cnt -> rowptr (exclusive, rowptr[0]=0) ----
__global__ void k_scanf(const int* __restrict__ cnt, const int* __restrict__ bsum,
                        int* __restrict__ rowptr, int n, int nb) {
  int t = threadIdx.x, lane = t & 63, w = t >> 6;
  __shared__ int ws1[4], ws2[4], sboff;

  int v0 = (t < nb) ? bsum[t] : 0;
  int s0 = v0;
  #pragma unroll
  for (int off = 1; off < 64; off <<= 1) {
    int u = __shfl_up(s0, off, 64);
    if (lane >= off) s0 += u;
  }
  if (lane == 63) ws1[w] = s0;
  __syncthreads();
  if (t == blockIdx.x) {
    int add0 = 0;
    for (int j = 0; j < w; ++j) add0 += ws1[j];
    sboff = s0 + add0 - v0;            // exclusive offset for this block
  }
  __syncthreads();

  int i = blockIdx.x * 256 + t;
  int v = (i < n) ? cnt[(size_t)i * CPAD] : 0;
  int s = v;
  #pragma unroll
  for (int off = 1; off < 64; off <<= 1) {
    int u = __shfl_up(s, off, 64);
    if (lane >= off) s += u;
  }
  if (lane == 63) ws2[w] = s;
  __syncthreads();
  int add = sboff;
  for (int j = 0; j < w; ++j) add += ws2[j];
  if (i < n) rowptr[i + 1] = s + add;
  if (i == 0) rowptr[0] = 0;
}

// ---- counting-sort fill of CSR neighbor lists (padded cursors, u16 src) ----
__global__ void k_fill(const int* __restrict__ src, const int* __restrict__ dst,
                       const int* __restrict__ rowptr, int* __restrict__ cursor,
                       unsigned short* __restrict__ csr, int E) {
  int e = blockIdx.x * 256 + threadIdx.x;
  if (e < E) {
    int d = dst[e];
    int pos = atomicAdd(&cursor[(size_t)d * CPAD], 1);
    csr[rowptr[d] + pos] = (unsigned short)src[e];   // src < 50000 < 65536
  }
}

// ---- bf16 accumulate helper ----
__device__ __forceinline__ void acc8(float* s, uint4 r) {
  const unsigned int u[4] = {r.x, r.y, r.z, r.w};
  #pragma unroll
  for (int k = 0; k < 4; ++k) {
    union { unsigned int u; float f; } lo, hi;
    lo.u = u[k] << 16;
    hi.u = u[k] & 0xffff0000u;
    s[2 * k]     += lo.f;
    s[2 * k + 1] += hi.f;
  }
}

// =====================================================================
// XCD channel-sliced aggregate, v2 (lane-local accumulation).
// Slice s = channels [s*64,(s+1)*64), processed ONLY by blocks with
// bid%8==s -> XCD s; per-XCD gather footprint 6.4MB (L2-resident).
// Wave = 8 nodes x 8 lanes: group g owns node base+g; lane li owns
// channels [li*8,li*8+8). Accumulation is LANE-LOCAL (no reduce);
// per-wave fixed cost amortized over 8 nodes (fixes R7's 66% VALUBusy).
// csr index loads are group-uniform 2B broadcasts.
// =====================================================================
__global__ __launch_bounds__(256) void k_aggregate(
    const unsigned short* __restrict__ xb,
    const int* __restrict__ rowptr,
    const unsigned short* __restrict__ csr,
    unsigned short* __restrict__ meanS, int Nn) {
  const int s  = blockIdx.x & 7;                 // slice == XCD (bid%8)
  const int nb = blockIdx.x >> 3;                // node-block (32 nodes)
  const int wv = threadIdx.x >> 6;               // 4 waves/block
  const int lane = threadIdx.x & 63;
  const int g = lane >> 3, li = lane & 7;
  const int node = nb * 32 + wv * 8 + g;         // this group's node

  int beg = 0, deg = 0;
  if (node < Nn) {
    beg = rowptr[node];
    deg = rowptr[node + 1] - beg;
  }
  float acc[8] = {};
  const unsigned short* __restrict__ xs = xb + s * 64 + li * 8;

  int j = 0;
  for (; j + 2 <= deg; j += 2) {                 // 2 gathers in flight/group
    int i0 = (int)csr[beg + j];
    int i1 = (int)csr[beg + j + 1];
    uint4 r0 = *reinterpret_cast<const uint4*>(xs + (size_t)i0 * CI);
    uint4 r1 = *reinterpret_cast<const uint4*>(xs + (size_t)i1 * CI);
    acc8(acc, r0);
    acc8(acc, r1);
  }
  if (j < deg) {
    int i0 = (int)csr[beg + j];
    uint4 r0 = *reinterpret_cast<const uint4*>(xs + (size_t)i0 * CI);
    acc8(acc, r0);
  }

  if (node < Nn) {
    const float inv = 1.f / fmaxf((float)deg, 1.f);
    unsigned short ob[8];
    #pragma unroll
    for (int k = 0; k < 8; ++k) ob[k] = f2bf_bits(acc[k] * inv);
    uint4 w;
    w.x = (unsigned int)ob[0] | ((unsigned int)ob[1] << 16);
    w.y = (unsigned int)ob[2] | ((unsigned int)ob[3] << 16);
    w.z = (unsigned int)ob[4] | ((unsigned int)ob[5] << 16);
    w.w = (unsigned int)ob[6] | ((unsigned int)ob[7] << 16);
    *reinterpret_cast<uint4*>(meanS + ((size_t)s * Nn + node) * 64 + li * 8) = w;
  }
}

// ---- bf16 MFMA GEMM, pipelined: out[M][512] = [xb|mean][M][1024].Wb^T + b ----
// BM=256 BN=128 BK=64, 8 waves (512 thr), 3-slot LDS ring (144 KB),
// counted vmcnt(12). Mean half read from SLICED layout meanS[8][Nn][64].
#define BM 256
#define BN 128
#define BK 64
#define SLOT_SH 24576     // shorts per slot: A 16384 (32KB) + B 8192 (16KB)
#define BOFF 16384        // B base within slot (shorts)
#define EPAD 132          // f32 row pitch for epilogue LDS tile

#define WAITV(N) asm volatile("s_waitcnt vmcnt(" #N ")" ::: "memory")

__global__ __launch_bounds__(512) void k_gemm(
    const unsigned short* __restrict__ xb,
    const unsigned short* __restrict__ meanS,
    const unsigned short* __restrict__ Wb,
    const float* __restrict__ bias,
    float* __restrict__ out, int M) {
  __shared__ unsigned short lds[3 * SLOT_SH];   // 144 KB
  const int tid = threadIdx.x;

  // grid = 196 m-tiles x 4 n-tiles = 784 = 8*98: chunked XCD swizzle
  const int wg = (blockIdx.x & 7) * 98 + (blockIdx.x >> 3);
  const int tm = wg >> 2, tn = wg & 3;
  const int m0 = tm * BM, n0 = tn * BN;
  const int lane = tid & 63, wvid = tid >> 6;
  const int wm = wvid >> 2, wn = wvid & 3;      // 2M x 4N waves
  const int lrow = lane & 15;

  // staging geometry (T2 chunk swizzle: src chunk = stored-chunk ^ (row&7))
  int gra[4], asrc8[4];
  #pragma unroll
  for (int i = 0; i < 4; ++i) {
    int idx = i * 512 + tid;
    int r = idx >> 3;
    asrc8[i] = ((idx & 7) ^ (r & 7)) * 8;
    int g = m0 + r;
    gra[i] = g < M ? g : M - 1;
  }
  int brow[2], bsrc8[2];
  #pragma unroll
  for (int i = 0; i < 2; ++i) {
    int idx = i * 512 + tid;
    int r = idx >> 3;
    brow[i] = r;
    bsrc8[i] = ((idx & 7) ^ (r & 7)) * 8;
  }

  const size_t Nn64 = (size_t)M * 64;

  f32x4 acc[8][2] = {};

  // stage K-tile kt into slot sl
  auto stage = [&](int kt, int sl) {
    unsigned short* sa = &lds[sl * SLOT_SH];
    unsigned short* sb = sa + BOFF;
    if (kt < 8) {
      const int ka = kt * 64;
      #pragma unroll
      for (int i = 0; i < 4; ++i)
        __builtin_amdgcn_global_load_lds(
          (const AS1 unsigned int*)(uintptr_t)(xb + (size_t)gra[i] * CI + ka + asrc8[i]),
          (AS3 unsigned int*)(uintptr_t)(&sa[(size_t)(i * 512 + tid) * 8]), 16, 0, 0);
    } else {
      const unsigned short* __restrict__ A = meanS + (size_t)(kt - 8) * Nn64;
      #pragma unroll
      for (int i = 0; i < 4; ++i)
        __builtin_amdgcn_global_load_lds(
          (const AS1 unsigned int*)(uintptr_t)(A + (size_t)gra[i] * 64 + asrc8[i]),
          (AS3 unsigned int*)(uintptr_t)(&sa[(size_t)(i * 512 + tid) * 8]), 16, 0, 0);
    }
    const int kw = kt * 64;
    #pragma unroll
    for (int i = 0; i < 2; ++i)
      __builtin_amdgcn_global_load_lds(
        (const AS1 unsigned int*)(uintptr_t)(Wb + (size_t)(n0 + brow[i]) * (2 * CI) + kw + bsrc8[i]),
        (AS3 unsigned int*)(uintptr_t)(&sb[(size_t)(i * 512 + tid) * 8]), 16, 0, 0);
  };

  auto compute = [&](int sl) {
    const unsigned short* __restrict__ La = &lds[sl * SLOT_SH];
    const unsigned short* __restrict__ Lb = La + BOFF;
    #pragma unroll
    for (int kk = 0; kk < 2; ++kk) {
      const int crd = kk * 4 + (lane >> 4);
      bf16x8 af[8], bf[2];
      #pragma unroll
      for (int mi = 0; mi < 8; ++mi) {
        const int rr = wm * 128 + mi * 16 + lrow;
        af[mi] = *reinterpret_cast<const bf16x8*>(&La[rr * BK + ((crd ^ (rr & 7)) * 8)]);
      }
      #pragma unroll
      for (int ni = 0; ni < 2; ++ni) {
        const int rb = wn * 32 + ni * 16 + lrow;
        bf[ni] = *reinterpret_cast<const bf16x8*>(&Lb[rb * BK + ((crd ^ (rb & 7)) * 8)]);
      }
      __builtin_amdgcn_s_setprio(1);
      #pragma unroll
      for (int mi = 0; mi < 8; ++mi)
        #pragma unroll
        for (int ni = 0; ni < 2; ++ni)
          acc[mi][ni] = __builtin_amdgcn_mfma_f32_16x16x32_bf16(af[mi], bf[ni], acc[mi][ni], 0, 0, 0);
      __builtin_amdgcn_s_setprio(0);
    }
  };

  // prologue: 2 tiles in flight
  stage(0, 0);
  stage(1, 1);

  #pragma unroll
  for (int t = 0; t < 16; ++t) {
    if (t < 14) {
      stage(t + 2, (t + 2) % 3);
      WAITV(12);                    // 12 loads (2 tiles) stay in flight
    } else if (t == 14) {
      WAITV(6);
    } else {
      WAITV(0);
    }
    __builtin_amdgcn_s_barrier();
    __builtin_amdgcn_sched_barrier(0);
    compute(t % 3);
    __builtin_amdgcn_sched_barrier(0);
    __builtin_amdgcn_s_barrier();
  }

  // ---- LDS-staged epilogue: 8 chunks of 32 rows x 128 cols ----
  __syncthreads();
  float* ldsf = reinterpret_cast<float*>(&lds[0]);   // 32*EPAD*4 = 16.9 KB
  const int lj = lane >> 4;
  float bv[2];
  #pragma unroll
  for (int ni = 0; ni < 2; ++ni) bv[ni] = bias[n0 + wn * 32 + ni * 16 + lrow];

  #pragma unroll
  for (int c = 0; c < 8; ++c) {
    if (wm == (c >> 2)) {
      #pragma unroll
      for (int mi2 = 0; mi2 < 2; ++mi2) {
        const int mi = (c & 3) * 2 + mi2;
        #pragma unroll
        for (int ni = 0; ni < 2; ++ni)
          #pragma unroll
          for (int j = 0; j < 4; ++j)
            ldsf[(mi2 * 16 + lj * 4 + j) * EPAD + wn * 32 + ni * 16 + lrow] = acc[mi][ni][j] + bv[ni];
      }
    }
    __syncthreads();
    #pragma unroll
    for (int p = 0; p < 2; ++p) {
      int linear = p * 512 + tid;           // 0..1023
      int rl = linear >> 5;                 // 0..31
      int c4 = (linear & 31) << 2;          // 0..124
      int row = m0 + c * 32 + rl;
      if (row < M) {
        float4 v = *reinterpret_cast<const float4*>(&ldsf[rl * EPAD + c4]);
        *reinterpret_cast<float4*>(&out[(size_t)row * CO + n0 + c4]) = v;
      }
    }
    __syncthreads();
  }
}

extern "C" void kernel_launch(void* const* d_in, const int* in_sizes, int n_in,
                              void* d_out, int out_size, void* d_ws, size_t ws_size,
                              hipStream_t stream) {
  (void)n_in; (void)out_size; (void)ws_size;
  const float* x    = (const float*)d_in[0];
  const int*   ei   = (const int*)d_in[1];
  const float* W    = (const float*)d_in[2];
  const float* bias = (const float*)d_in[3];
  float* out = (float*)d_out;

  const int Nn = in_sizes[0] / CI;     // 50000
  const int E  = in_sizes[1] / 2;      // 800000
  const int* src = ei;
  const int* dst = ei + E;

  const int nblk = (Nn + 255) / 256;   // 196 scan blocks

  // workspace layout (~110 MB):
  int* cnt    = (int*)d_ws;                      // [Nn*CPAD]
  int* cursor = cnt + (size_t)Nn * CPAD;         // [Nn*CPAD]
  int* rowptr = cursor + (size_t)Nn * CPAD;      // [Nn+1]
  int* bsum   = rowptr + (Nn + 1);               // [nblk]
  uintptr_t p = (uintptr_t)(bsum + nblk);
  p = (p + 255) & ~(uintptr_t)255;
  unsigned short* csr = (unsigned short*)p;             // [E] u16 src ids
  p = (uintptr_t)(csr + E);
  p = (p + 255) & ~(uintptr_t)255;
  unsigned short* xb    = (unsigned short*)p;           // [Nn*CI] bf16
  unsigned short* meanS = xb + (size_t)Nn * CI;         // [8*Nn*64] bf16 sliced
  unsigned short* Wb    = meanS + (size_t)Nn * CI;      // [CO*2CI] bf16

  hipMemsetAsync(cnt, 0, (size_t)2 * Nn * CPAD * sizeof(int), stream);  // cnt + cursor

  const int nx4 = (Nn * CI) / 4;          // 6,400,000
  const int nw4 = (CO * 2 * CI) / 4;      // 131,072
  const int bx = (nx4 + 255) / 256;       // 25000
  const int bw = (nw4 + 255) / 256;       // 512
  const int be = (E + 255) / 256;         // 3125
  k_prep<<<bx + bw + be, 256, 0, stream>>>(x, xb, nx4, W, Wb, nw4, dst, cnt, E, bx, bw);
  k_bsum<<<nblk, 256, 0, stream>>>(cnt, bsum, Nn);
  k_scanf<<<nblk, 256, 0, stream>>>(cnt, bsum, rowptr, Nn, nblk);
  k_fill<<<(E + 255) / 256, 256, 0, stream>>>(src, dst, rowptr, cursor, csr, E);

  const int nab = ((Nn + 31) / 32) * 8;   // 1563 node-blocks x 8 slices
  k_aggregate<<<nab, 256, 0, stream>>>(xb, rowptr, csr, meanS, Nn);

  const int mtiles = (Nn + BM - 1) / BM;  // 196
  k_gemm<<<mtiles * (CO / BN), 512, 0, stream>>>(xb, meanS, Wb, bias, out, Nn);
}

// Round 9
// 258.264 us; speedup vs baseline: 1.4152x; 1.0671x over previous
//
#include <hip/hip_runtime.h>
#include <stdint.h>

// Problem constants (PureSAGEConv): N=50000, C_in=512, C_out=512, E=800000
#define CI 512
#define CO 512
#define CPAD 8   // counter padding stride (ints): 4 counters per 128B line

typedef __attribute__((ext_vector_type(4))) float f32x4;
typedef __attribute__((ext_vector_type(8))) __bf16 bf16x8;

#define AS1 __attribute__((address_space(1)))
#define AS3 __attribute__((address_space(3)))

__device__ __forceinline__ unsigned short f2bf_bits(float f) {
  union { float f; unsigned int u; } v; v.f = f;
  unsigned int u = v.u;
  unsigned int lsb = (u >> 16) & 1u;
  u += 0x7fffu + lsb;                 // round-to-nearest-even
  return (unsigned short)(u >> 16);
}

// ---- merged: convert x, convert W, degree histogram (block-range split) ----
__global__ void k_prep(const float* __restrict__ x, unsigned short* __restrict__ xb, int nx4,
                       const float* __restrict__ W, unsigned short* __restrict__ Wb, int nw4,
                       const int* __restrict__ dst, int* __restrict__ cnt, int E,
                       int bx, int bw) {
  const int b = blockIdx.x;
  if (b < bx) {
    int i = b * 256 + threadIdx.x;
    if (i < nx4) {
      float4 v = reinterpret_cast<const float4*>(x)[i];
      ushort4 o;
      o.x = f2bf_bits(v.x); o.y = f2bf_bits(v.y);
      o.z = f2bf_bits(v.z); o.w = f2bf_bits(v.w);
      reinterpret_cast<ushort4*>(xb)[i] = o;
    }
  } else if (b < bx + bw) {
    int i = (b - bx) * 256 + threadIdx.x;
    if (i < nw4) {
      float4 v = reinterpret_cast<const float4*>(W)[i];
      ushort4 o;
      o.x = f2bf_bits(v.x); o.y = f2bf_bits(v.y);
      o.z = f2bf_bits(v.z); o.w = f2bf_bits(v.w);
      reinterpret_cast<ushort4*>(Wb)[i] = o;
    }
  } else {
    int e = (b - bx - bw) * 256 + threadIdx.x;
    if (e < E) atomicAdd(&cnt[dst[e] * CPAD], 1);
  }
}

// ---- per-256-node block sums of (padded) degree counters ----
__global__ void k_bsum(const int* __restrict__ cnt, int* __restrict__ bsum, int n) {
  int t = threadIdx.x;
  int i = blockIdx.x * 256 + t;
  int v = (i < n) ? cnt[(size_t)i * CPAD] : 0;
  #pragma unroll
  for (int off = 32; off; off >>= 1) v += __shfl_down(v, off, 64);
  __shared__ int ws[4];
  if ((t & 63) == 0) ws[t >> 6] = v;
  __syncthreads();
  if (t == 0) bsum[blockIdx.x] = ws[0] + ws[1] + ws[2] + ws[3];
}

// ---- merged scan: each block redundantly scans bsum (nb<=256), then
//      block-local scan of padded cnt -> rowptr (exclusive, rowptr[0]=0) ----
__global__ void k_scanf(const int* __restrict__ cnt, const int* __restrict__ bsum,
                        int* __restrict__ rowptr, int n, int nb) {
  int t = threadIdx.x, lane = t & 63, w = t >> 6;
  __shared__ int ws1[4], ws2[4], sboff;

  int v0 = (t < nb) ? bsum[t] : 0;
  int s0 = v0;
  #pragma unroll
  for (int off = 1; off < 64; off <<= 1) {
    int u = __shfl_up(s0, off, 64);
    if (lane >= off) s0 += u;
  }
  if (lane == 63) ws1[w] = s0;
  __syncthreads();
  if (t == blockIdx.x) {
    int add0 = 0;
    for (int j = 0; j < w; ++j) add0 += ws1[j];
    sboff = s0 + add0 - v0;            // exclusive offset for this block
  }
  __syncthreads();

  int i = blockIdx.x * 256 + t;
  int v = (i < n) ? cnt[(size_t)i * CPAD] : 0;
  int s = v;
  #pragma unroll
  for (int off = 1; off < 64; off <<= 1) {
    int u = __shfl_up(s, off, 64);
    if (lane >= off) s += u;
  }
  if (lane == 63) ws2[w] = s;
  __syncthreads();
  int add = sboff;
  for (int j = 0; j < w; ++j) add += ws2[j];
  if (i < n) rowptr[i + 1] = s + add;
  if (i == 0) rowptr[0] = 0;
}

// ---- counting-sort fill of CSR neighbor lists (padded cursors, u16 src) ----
__global__ void k_fill(const int* __restrict__ src, const int* __restrict__ dst,
                       const int* __restrict__ rowptr, int* __restrict__ cursor,
                       unsigned short* __restrict__ csr, int E) {
  int e = blockIdx.x * 256 + threadIdx.x;
  if (e < E) {
    int d = dst[e];
    int pos = atomicAdd(&cursor[(size_t)d * CPAD], 1);
    csr[rowptr[d] + pos] = (unsigned short)src[e];   // src < 50000 < 65536
  }
}

// ---- bf16 accumulate helper ----
__device__ __forceinline__ void acc8(float* s, uint4 r) {
  const unsigned int u[4] = {r.x, r.y, r.z, r.w};
  #pragma unroll
  for (int k = 0; k < 4; ++k) {
    union { unsigned int u; float f; } lo, hi;
    lo.u = u[k] << 16;
    hi.u = u[k] & 0xffff0000u;
    s[2 * k]     += lo.f;
    s[2 * k + 1] += hi.f;
  }
}

// =====================================================================
// XCD channel-sliced aggregate (lane-local accumulation). Slice s =
// channels [s*64,(s+1)*64), processed ONLY by blocks with bid%8==s ->
// XCD s; per-XCD gather footprint 6.4MB (L2-resident). Wave = 8 nodes
// x 8 lanes; accumulation LANE-LOCAL (no reduce). FETCH 373->180MB.
// =====================================================================
__global__ __launch_bounds__(256) void k_aggregate(
    const unsigned short* __restrict__ xb,
    const int* __restrict__ rowptr,
    const unsigned short* __restrict__ csr,
    unsigned short* __restrict__ meanS, int Nn) {
  const int s  = blockIdx.x & 7;                 // slice == XCD (bid%8)
  const int nb = blockIdx.x >> 3;                // node-block (32 nodes)
  const int wv = threadIdx.x >> 6;               // 4 waves/block
  const int lane = threadIdx.x & 63;
  const int g = lane >> 3, li = lane & 7;
  const int node = nb * 32 + wv * 8 + g;         // this group's node

  int beg = 0, deg = 0;
  if (node < Nn) {
    beg = rowptr[node];
    deg = rowptr[node + 1] - beg;
  }
  float acc[8] = {};
  const unsigned short* __restrict__ xs = xb + s * 64 + li * 8;

  int j = 0;
  for (; j + 2 <= deg; j += 2) {                 // 2 gathers in flight/group
    int i0 = (int)csr[beg + j];
    int i1 = (int)csr[beg + j + 1];
    uint4 r0 = *reinterpret_cast<const uint4*>(xs + (size_t)i0 * CI);
    uint4 r1 = *reinterpret_cast<const uint4*>(xs + (size_t)i1 * CI);
    acc8(acc, r0);
    acc8(acc, r1);
  }
  if (j < deg) {
    int i0 = (int)csr[beg + j];
    uint4 r0 = *reinterpret_cast<const uint4*>(xs + (size_t)i0 * CI);
    acc8(acc, r0);
  }

  if (node < Nn) {
    const float inv = 1.f / fmaxf((float)deg, 1.f);
    unsigned short ob[8];
    #pragma unroll
    for (int k = 0; k < 8; ++k) ob[k] = f2bf_bits(acc[k] * inv);
    uint4 w;
    w.x = (unsigned int)ob[0] | ((unsigned int)ob[1] << 16);
    w.y = (unsigned int)ob[2] | ((unsigned int)ob[3] << 16);
    w.z = (unsigned int)ob[4] | ((unsigned int)ob[5] << 16);
    w.w = (unsigned int)ob[6] | ((unsigned int)ob[7] << 16);
    *reinterpret_cast<uint4*>(meanS + ((size_t)s * Nn + node) * 64 + li * 8) = w;
  }
}

// ---- bf16 MFMA GEMM v3: 2 blocks/CU for cross-block stall hiding ----
// BM=128 BN=128 BK=64, 256 thr (4 waves, 2Mx2N: A-dup 4x->2x),
// double-buffered 2x32KB=64KB LDS, counted WAITV(8) ring.
#define BM 128
#define BN 128
#define BK 64
#define SLOT_SH 16384     // shorts per slot: A 8192 (16KB) + B 8192 (16KB)
#define BOFF 8192         // B base within slot (shorts)
#define EPAD 132          // f32 row pitch for epilogue LDS tile

#define WAITV(N) asm volatile("s_waitcnt vmcnt(" #N ")" ::: "memory")

__global__ __launch_bounds__(256) void k_gemm(
    const unsigned short* __restrict__ xb,
    const unsigned short* __restrict__ meanS,
    const unsigned short* __restrict__ Wb,
    const float* __restrict__ bias,
    float* __restrict__ out, int M) {
  __shared__ unsigned short lds[2 * SLOT_SH];   // 64 KB
  const int tid = threadIdx.x;
  const int ntn = CO / BN;                       // 4

  // Bijective XCD-aware swizzle (m204; nwg=1564 not %8==0).
  const int nwg = gridDim.x;
  const int q = nwg >> 3, r = nwg & 7;
  const int xcd = blockIdx.x & 7, lid = blockIdx.x >> 3;
  const int wg = (xcd < r ? xcd * (q + 1) : r * (q + 1) + (xcd - r) * q) + lid;

  const int tm = wg / ntn, tn = wg % ntn;
  const int m0 = tm * BM, n0 = tn * BN;
  const int lane = tid & 63, wvid = tid >> 6;
  const int wm = wvid >> 1, wn = wvid & 1;       // 2M x 2N waves, 64x64 each
  const int lrow = lane & 15;

  // staging geometry (T2 chunk swizzle): 128 rows x 64 cols per operand,
  // 4 rounds x (256 thr x 16B). src chunk = stored-chunk ^ (row&7).
  int arow[4], gra[4], scol8[4];
  #pragma unroll
  for (int i = 0; i < 4; ++i) {
    int idx = i * 256 + tid;
    int rr = idx >> 3;
    arow[i] = rr;
    scol8[i] = ((idx & 7) ^ (rr & 7)) * 8;
    int g = m0 + rr;
    gra[i] = g < M ? g : M - 1;
  }

  const size_t Nn64 = (size_t)M * 64;

  f32x4 acc[4][4] = {};

  // stage K-tile kt into slot sl (8 global_load_lds per thread)
  auto stage = [&](int kt, int sl) {
    unsigned short* sa = &lds[sl * SLOT_SH];
    unsigned short* sb = sa + BOFF;
    if (kt < 8) {
      const int ka = kt * 64;
      #pragma unroll
      for (int i = 0; i < 4; ++i)
        __builtin_amdgcn_global_load_lds(
          (const AS1 unsigned int*)(uintptr_t)(xb + (size_t)gra[i] * CI + ka + scol8[i]),
          (AS3 unsigned int*)(uintptr_t)(&sa[(size_t)(i * 256 + tid) * 8]), 16, 0, 0);
    } else {
      const unsigned short* __restrict__ A = meanS + (size_t)(kt - 8) * Nn64;
      #pragma unroll
      for (int i = 0; i < 4; ++i)
        __builtin_amdgcn_global_load_lds(
          (const AS1 unsigned int*)(uintptr_t)(A + (size_t)gra[i] * 64 + scol8[i]),
          (AS3 unsigned int*)(uintptr_t)(&sa[(size_t)(i * 256 + tid) * 8]), 16, 0, 0);
    }
    const int kw = kt * 64;
    #pragma unroll
    for (int i = 0; i < 4; ++i)
      __builtin_amdgcn_global_load_lds(
        (const AS1 unsigned int*)(uintptr_t)(Wb + (size_t)(n0 + arow[i]) * (2 * CI) + kw + scol8[i]),
        (AS3 unsigned int*)(uintptr_t)(&sb[(size_t)(i * 256 + tid) * 8]), 16, 0, 0);
  };

  auto compute = [&](int sl) {
    const unsigned short* __restrict__ La = &lds[sl * SLOT_SH];
    const unsigned short* __restrict__ Lb = La + BOFF;
    #pragma unroll
    for (int kk = 0; kk < 2; ++kk) {
      const int crd = kk * 4 + (lane >> 4);
      bf16x8 af[4], bf[4];
      #pragma unroll
      for (int mi = 0; mi < 4; ++mi) {
        const int rr = wm * 64 + mi * 16 + lrow;
        af[mi] = *reinterpret_cast<const bf16x8*>(&La[rr * BK + ((crd ^ (rr & 7)) * 8)]);
      }
      #pragma unroll
      for (int ni = 0; ni < 4; ++ni) {
        const int rb = wn * 64 + ni * 16 + lrow;
        bf[ni] = *reinterpret_cast<const bf16x8*>(&Lb[rb * BK + ((crd ^ (rb & 7)) * 8)]);
      }
      __builtin_amdgcn_s_setprio(1);
      #pragma unroll
      for (int mi = 0; mi < 4; ++mi)
        #pragma unroll
        for (int ni = 0; ni < 4; ++ni)
          acc[mi][ni] = __builtin_amdgcn_mfma_f32_16x16x32_bf16(af[mi], bf[ni], acc[mi][ni], 0, 0, 0);
      __builtin_amdgcn_s_setprio(0);
    }
  };

  stage(0, 0);                         // prologue: 1 tile in flight

  #pragma unroll
  for (int t = 0; t < 16; ++t) {
    if (t < 15) {
      stage(t + 1, (t + 1) & 1);       // fill the other buffer
      WAITV(8);                        // tile t's 8 loads done; t+1's in flight
    } else {
      WAITV(0);
    }
    __builtin_amdgcn_s_barrier();      // tile t ready for ALL waves
    __builtin_amdgcn_sched_barrier(0);
    compute(t & 1);
    __builtin_amdgcn_sched_barrier(0);
    __builtin_amdgcn_s_barrier();      // all waves done reading slot t&1
  }

  // ---- LDS-staged epilogue: 8 chunks of 16 rows x 128 cols ----
  __syncthreads();
  float* lds_c = reinterpret_cast<float*>(&lds[0]);   // 16*EPAD*4 = 8448B
  const int lj = lane >> 4;
  float bv[4];
  #pragma unroll
  for (int ni = 0; ni < 4; ++ni) bv[ni] = bias[n0 + wn * 64 + ni * 16 + lrow];

  #pragma unroll
  for (int cw = 0; cw < 2; ++cw) {
    #pragma unroll
    for (int mi = 0; mi < 4; ++mi) {
      if (wm == cw) {
        #pragma unroll
        for (int ni = 0; ni < 4; ++ni)
          #pragma unroll
          for (int j = 0; j < 4; ++j)
            lds_c[(lj * 4 + j) * EPAD + wn * 64 + ni * 16 + lrow] = acc[mi][ni][j] + bv[ni];
      }
      __syncthreads();
      #pragma unroll
      for (int p = 0; p < 2; ++p) {
        int linear = p * 256 + tid;          // 0..511
        int rl = linear >> 5;                // 0..15
        int c4 = (linear & 31) << 2;         // 0..124
        int row = m0 + cw * 64 + mi * 16 + rl;
        if (row < M) {
          float4 v = *reinterpret_cast<const float4*>(&lds_c[rl * EPAD + c4]);
          *reinterpret_cast<float4*>(&out[(size_t)row * CO + n0 + c4]) = v;
        }
      }
      __syncthreads();
    }
  }
}

extern "C" void kernel_launch(void* const* d_in, const int* in_sizes, int n_in,
                              void* d_out, int out_size, void* d_ws, size_t ws_size,
                              hipStream_t stream) {
  (void)n_in; (void)out_size; (void)ws_size;
  const float* x    = (const float*)d_in[0];
  const int*   ei   = (const int*)d_in[1];
  const float* W    = (const float*)d_in[2];
  const float* bias = (const float*)d_in[3];
  float* out = (float*)d_out;

  const int Nn = in_sizes[0] / CI;     // 50000
  const int E  = in_sizes[1] / 2;      // 800000
  const int* src = ei;
  const int* dst = ei + E;

  const int nblk = (Nn + 255) / 256;   // 196 scan blocks

  // workspace layout (~110 MB):
  int* cnt    = (int*)d_ws;                      // [Nn*CPAD]
  int* cursor = cnt + (size_t)Nn * CPAD;         // [Nn*CPAD]
  int* rowptr = cursor + (size_t)Nn * CPAD;      // [Nn+1]
  int* bsum   = rowptr + (Nn + 1);               // [nblk]
  uintptr_t p = (uintptr_t)(bsum + nblk);
  p = (p + 255) & ~(uintptr_t)255;
  unsigned short* csr = (unsigned short*)p;             // [E] u16 src ids
  p = (uintptr_t)(csr + E);
  p = (p + 255) & ~(uintptr_t)255;
  unsigned short* xb    = (unsigned short*)p;           // [Nn*CI] bf16
  unsigned short* meanS = xb + (size_t)Nn * CI;         // [8*Nn*64] bf16 sliced
  unsigned short* Wb    = meanS + (size_t)Nn * CI;      // [CO*2CI] bf16

  hipMemsetAsync(cnt, 0, (size_t)2 * Nn * CPAD * sizeof(int), stream);  // cnt + cursor

  const int nx4 = (Nn * CI) / 4;          // 6,400,000
  const int nw4 = (CO * 2 * CI) / 4;      // 131,072
  const int bx = (nx4 + 255) / 256;       // 25000
  const int bw = (nw4 + 255) / 256;       // 512
  const int be = (E + 255) / 256;         // 3125
  k_prep<<<bx + bw + be, 256, 0, stream>>>(x, xb, nx4, W, Wb, nw4, dst, cnt, E, bx, bw);
  k_bsum<<<nblk, 256, 0, stream>>>(cnt, bsum, Nn);
  k_scanf<<<nblk, 256, 0, stream>>>(cnt, bsum, rowptr, Nn, nblk);
  k_fill<<<(E + 255) / 256, 256, 0, stream>>>(src, dst, rowptr, cursor, csr, E);

  const int nab = ((Nn + 31) / 32) * 8;   // 1563 node-blocks x 8 slices
  k_aggregate<<<nab, 256, 0, stream>>>(xb, rowptr, csr, meanS, Nn);

  const int mtiles = (Nn + BM - 1) / BM;  // 391
  k_gemm<<<mtiles * (CO / BN), 256, 0, stream>>>(xb, meanS, Wb, bias, out, Nn);
}